// Round 10
// baseline (166.921 us; speedup 1.0000x reference)
//
#include <hip/hip_runtime.h>
#include <stdint.h>

typedef __bf16 bf16x8 __attribute__((ext_vector_type(8)));
typedef float  f32x4  __attribute__((ext_vector_type(4)));
typedef uint32_t u32x4 __attribute__((ext_vector_type(4)));

__device__ __forceinline__ uint16_t f2bf(float f) {
    uint32_t u = __builtin_bit_cast(uint32_t, f);
    u += 0x7FFFu + ((u >> 16) & 1u);          // round-to-nearest-even
    return (uint16_t)(u >> 16);
}

// ---------------------------------------------------------------------------
// Kernel 1: Q [b][c 256][i 32][j 32] f32 -> Qt [b][ih 2][j 32][ch 32][il 16][8] bf16
//   where c = ch*8 + t, i = ih*16 + il.  Corr's B-fragment load = 1 KB contiguous.
//   Also zeroes the output tensor (replaces the separate hipMemsetAsync).
// ---------------------------------------------------------------------------
__global__ __launch_bounds__(256) void qtrans_kernel(const float* __restrict__ Q,
                                                     uint16_t* __restrict__ Qt,
                                                     float* __restrict__ out) {
    // T[c8 8][i 32][j 33] f32, c8-stride 1064 so bank = 8*c8 + i + j
    __shared__ float T[8 * 1064];
    const int ch = blockIdx.x, b = blockIdx.y;
    const int tid = threadIdx.x;

    // fold in out-zeroing: 512 blocks x 256 threads = 131072 >= 67600
    {
        int g = (b * 32 + ch) * 256 + tid;
        if (g < 67600) out[g] = 0.f;
    }

    const float* src = Q + ((size_t)(b * 256 + ch * 8)) * 1024;
    #pragma unroll
    for (int it = 0; it < 32; ++it) {                  // 8192 f32, coalesced
        int r = tid + it * 256;
        int c8 = r >> 10, rem = r & 1023;
        T[c8 * 1064 + (rem >> 5) * 33 + (rem & 31)] = src[(size_t)c8 * 1024 + rem];
    }
    __syncthreads();

    uint32_t* dst = (uint32_t*)Qt;                     // write bf16 pairs
    #pragma unroll
    for (int it = 0; it < 16; ++it) {                  // 4096 pairs
        int o2 = tid + it * 256;
        int t  = (o2 & 3) * 2;
        int il = (o2 >> 2) & 15;
        int j  = (o2 >> 6) & 31;
        int ih = (o2 >> 11) & 1;
        float v0 = T[t * 1064 + (ih * 16 + il) * 33 + j];
        float v1 = T[(t + 1) * 1064 + (ih * 16 + il) * 33 + j];
        uint32_t pk = (uint32_t)f2bf(v0) | ((uint32_t)f2bf(v1) << 16);
        size_t oi = ((((size_t)(b * 2 + ih) * 32 + j) * 32 + ch) * 16 + il) * 4 + (t >> 1);
        dst[oi] = pk;
    }
}

// ---------------------------------------------------------------------------
// Kernel 2: round-7 structure (grid 1024, b=bid&15 XCD swizzle, 40 KB LDS,
// 4 blocks/CU, B-fragment ping-pong + sched_barrier(0)) + ONE delta:
//   * c-split staging overlap WITHIN the block (r1's theory, retried with
//     r7's codegen fix).  z0 (slabs 0..15) staged before barrier 1; z1
//     (slabs 16..31) staged in 4 chunks interleaved into bodies 0..14
//     (load at n=0,4,8,12 -> pack+ds_write at n=2,6,10,14; ONE vs[8] chunk
//     live at a time).  Barrier at n==16; bodies 0..15 use only slabs 0..15
//     (s 0..3), bodies 16..31 only slabs 16..31 (s 4..7).  Chip-wide, z1's
//     ~5.3 us of HBM staging hides under z0's ~9 us of MFMA.
// REGISTER DISCIPLINE (r2/r8 lessons): acc 40 + B 2x16 + A 20 + vs 8 + addr
// ~= 115 <= 128 at 4 waves/SIMD.  Spill signature = WRITE_SIZE >> 20 MB.
// ---------------------------------------------------------------------------
__global__ __launch_bounds__(256, 4) void corr_kernel(const float* __restrict__ S,
                                                      const uint16_t* __restrict__ Qt,
                                                      float* __restrict__ out) {
    __shared__ __align__(16) char smem[40960];         // 40 KB -> 4 blocks/CU
    uint16_t* S_l = (uint16_t*)smem;                   // [slab 32][row 80][8] bf16
    float*    Pw  = (float*)smem;                      // overlay: [4][iv 32][x 80]

    const int bid = blockIdx.x;
    const int b = bid & 15, d = bid >> 4;
    const int tid = threadIdx.x, wave = tid >> 6, lane = tid & 63;
    const int l15 = lane & 15, l4 = lane >> 4;
    const int sx = lane;

    // ---- zero-fill pad rows 0..15 for all 32 slabs (8 KB)
    {
        const u32x4 z = {};
        for (int zi = tid; zi < 512; zi += 256) {
            int ch = zi >> 4, r = zi & 15;
            *(u32x4*)&S_l[ch * 640 + r * 8] = z;
        }
    }

    const float* sp = S + ((size_t)b * 256) * 4096 + (size_t)d * 64;

    // ---- stage z0 half: slabs 0..15  (c = 0..127)
    #pragma unroll
    for (int k = 0; k < 4; ++k) {
        const int ch = k * 4 + wave;                   // slab 0..15
        float v[8];
        #pragma unroll
        for (int cc = 0; cc < 8; ++cc)
            v[cc] = sp[(size_t)(ch * 8 + cc) * 4096 + sx];       // 256B coalesced
        u32x4 pk;
        #pragma unroll
        for (int q = 0; q < 4; ++q)
            pk[q] = (uint32_t)f2bf(v[2 * q]) | ((uint32_t)f2bf(v[2 * q + 1]) << 16);
        *(u32x4*)&S_l[ch * 640 + (sx + 16) * 8] = pk;            // contiguous 1KB/wave
    }

    // ---- B-fragment base.  Body (jj,s): off = (wave+jj*4)*4096 + s*512.
    //      Fragments: +0 (ih0,j0a), +131072 (ih1,j0a), +65536 (ih0,j0b),
    //      +196608 (ih1,j0b).
    const uint16_t* Bb = Qt + (size_t)b * 262144 + l4 * 128 + l15 * 8;

    // prefetch body 0's B-fragments BEFORE the barrier (no LDS dependency)
    // body 0: h=0, m=0 -> jj=0, s=wave, j0a=wave
    bf16x8 C0, C1, C2, C3;
    {
        const uint16_t* p0 = Bb + wave * 4096 + wave * 512;
        C0 = *(const bf16x8*)(p0);
        C1 = *(const bf16x8*)(p0 + 131072);
        C2 = *(const bf16x8*)(p0 + 65536);
        C3 = *(const bf16x8*)(p0 + 196608);
    }

    __syncthreads();                                   // z0 slabs visible

    f32x4 acc[5][2] = {};
    float vs[8];                                       // one z1 staging chunk

    #pragma unroll
    for (int n = 0; n < 32; ++n) {
        if (n == 16) __syncthreads();                  // z1 slabs visible

        // body coords: half h, jj = (n&15)>>2, s = h*4 + (((n&3)+wave)&3)
        const int h  = n >> 4;
        const int jj = (n & 15) >> 2;
        const int s  = h * 4 + (((n & 3) + wave) & 3); // per-wave s-rotation
        const int j0a = wave + jj * 4;                 // 0..15 ; j0b = j0a+16

        // ---- issue NEXT body's B-loads (ping-pong).  n=31 clamps (dead).
        const int nn = (n < 31) ? (n + 1) : 31;
        const int hn = nn >> 4;
        const int jn = (nn & 15) >> 2;
        const int sn = hn * 4 + (((nn & 3) + wave) & 3);
        const uint16_t* pn = Bb + (wave + jn * 4) * 4096 + sn * 512;
        bf16x8 N0 = *(const bf16x8*)(pn);
        bf16x8 N1 = *(const bf16x8*)(pn + 131072);
        bf16x8 N2 = *(const bf16x8*)(pn + 65536);
        bf16x8 N3 = *(const bf16x8*)(pn + 196608);

        // ---- z1 staging interleave (bodies 0..14 only; n compile-time)
        if (n == 0 || n == 4 || n == 8 || n == 12) {   // issue chunk k = n>>2
            const int ch = (n >> 2) * 4 + wave;        // local slab 0..15
            #pragma unroll
            for (int cc = 0; cc < 8; ++cc)
                vs[cc] = sp[(size_t)(128 + ch * 8 + cc) * 4096 + sx];
        }
        if (n == 2 || n == 6 || n == 10 || n == 14) {  // write chunk (n-2)>>2
            const int ch = ((n - 2) >> 2) * 4 + wave;
            u32x4 pk;
            #pragma unroll
            for (int q = 0; q < 4; ++q)
                pk[q] = (uint32_t)f2bf(vs[2 * q]) | ((uint32_t)f2bf(vs[2 * q + 1]) << 16);
            *(u32x4*)&S_l[(16 + ch) * 640 + (sx + 16) * 8] = pk;
        }

        // ---- A fragments from LDS (conflict-free b128), current body
        const int chb = (s * 4 + l4) * 640;
        bf16x8 A[5];
        #pragma unroll
        for (int t = 0; t < 5; ++t) {
            int rr = j0a + t * 16 + l15;               // <= 94
            rr = (rr < 80) ? rr : 0;                   // OOB -> zero-row
            A[t] = *(const bf16x8*)&S_l[chb + rr * 8];
        }
        __builtin_amdgcn_sched_barrier(0);             // pin loads/stage above MFMAs

        // ---- 18 MFMAs on the CURRENT (previously prefetched) B-fragments
        #pragma unroll
        for (int t = 0; t < 5; ++t) {
            acc[t][0] = __builtin_amdgcn_mfma_f32_16x16x32_bf16(A[t], C0, acc[t][0], 0, 0, 0);
            acc[t][1] = __builtin_amdgcn_mfma_f32_16x16x32_bf16(A[t], C1, acc[t][1], 0, 0, 0);
        }
        #pragma unroll
        for (int t = 1; t < 5; ++t) {
            acc[t - 1][0] = __builtin_amdgcn_mfma_f32_16x16x32_bf16(A[t], C2, acc[t - 1][0], 0, 0, 0);
            acc[t - 1][1] = __builtin_amdgcn_mfma_f32_16x16x32_bf16(A[t], C3, acc[t - 1][1], 0, 0, 0);
        }

        C0 = N0; C1 = N1; C2 = N2; C3 = N3;
    }

    // ---- merge 4 wave-partials in LDS, then atomic-add into out
    __syncthreads();
    {
        float* pw = Pw + wave * 2560;                  // [iv 32][x 80]
        #pragma unroll
        for (int m = 0; m < 5; ++m)
            #pragma unroll
            for (int n = 0; n < 2; ++n)
                *(f32x4*)&pw[(n * 16 + l15) * 80 + m * 16 + l4 * 4] = acc[m][n];
    }
    __syncthreads();
    for (int e = tid; e < 65 * 32; e += 256) {
        int x = e % 65, i = e / 65;
        int y = d - i + 16;
        if ((unsigned)y < 65u) {
            float v = Pw[0 * 2560 + i * 80 + x] + Pw[1 * 2560 + i * 80 + x]
                    + Pw[2 * 2560 + i * 80 + x] + Pw[3 * 2560 + i * 80 + x];
            atomicAdd(out + ((size_t)b * 4225 + (size_t)y * 65 + x), v);
        }
    }
}

// ---------------------------------------------------------------------------
// fp32 fallback (only if workspace is too small) — slow but exact
// ---------------------------------------------------------------------------
__global__ __launch_bounds__(256) void naive_kernel(const float* __restrict__ Q,
                                                    const float* __restrict__ S,
                                                    float* __restrict__ out) {
    int gid = blockIdx.x * 256 + threadIdx.x;
    if (gid >= 67600) return;
    int b = gid / 4225, r = gid % 4225, y = r / 65, x = r % 65;
    int jlo = 16 - x; if (jlo < 0) jlo = 0;
    int jhi = 80 - x; if (jhi > 32) jhi = 32;
    float acc = 0.f;
    for (int c = 0; c < 256; ++c) {
        const float* Sb = S + ((size_t)(b * 256 + c)) * 4096;
        const float* Qb = Q + ((size_t)(b * 256 + c)) * 1024;
        for (int i = 0; i < 32; ++i) {
            int dd = y + i - 16;
            if ((unsigned)dd >= 64u) continue;
            const float* Sr = Sb + dd * 64 + (x - 16);
            const float* Qr = Qb + i * 32;
            for (int j = jlo; j < jhi; ++j) acc += Sr[j] * Qr[j];
        }
    }
    out[gid] = acc;
}

extern "C" void kernel_launch(void* const* d_in, const int* in_sizes, int n_in,
                              void* d_out, int out_size, void* d_ws, size_t ws_size,
                              hipStream_t stream) {
    (void)in_sizes; (void)n_in; (void)out_size;
    const float* Q = (const float*)d_in[0];   // [16,256,32,32] f32
    const float* S = (const float*)d_in[1];   // [16,256,64,64] f32
    float* out = (float*)d_out;               // [16,1,65,65] f32

    const size_t QT_BYTES = (size_t)16 * 2 * 32 * 32 * 16 * 8 * 2;  // 8,388,608

    if (ws_size < QT_BYTES) {
        naive_kernel<<<(67600 + 255) / 256, 256, 0, stream>>>(Q, S, out);
        return;
    }
    uint16_t* Qt = (uint16_t*)d_ws;

    qtrans_kernel<<<dim3(32, 16), 256, 0, stream>>>(Q, Qt, out);
    corr_kernel<<<1024, 256, 0, stream>>>(S, Qt, out);
}

// Round 12
// 130.877 us; speedup vs baseline: 1.2754x; 1.2754x over previous
//
#include <hip/hip_runtime.h>
#include <stdint.h>

typedef __bf16 bf16x8 __attribute__((ext_vector_type(8)));
typedef float  f32x4  __attribute__((ext_vector_type(4)));
typedef uint32_t u32x4 __attribute__((ext_vector_type(4)));

__device__ __forceinline__ uint16_t f2bf(float f) {
    uint32_t u = __builtin_bit_cast(uint32_t, f);
    u += 0x7FFFu + ((u >> 16) & 1u);          // round-to-nearest-even
    return (uint16_t)(u >> 16);
}

// ---------------------------------------------------------------------------
// Kernel 1: Q [b][c 256][i 32][j 32] f32 -> Qt [b][ih 2][j 32][ch 32][il 16][8] bf16
//   where c = ch*8 + t, i = ih*16 + il.  Corr's B-fragment load = 1 KB contiguous.
//   Also zeroes the output tensor (replaces the separate hipMemsetAsync).
// ---------------------------------------------------------------------------
__global__ __launch_bounds__(256) void qtrans_kernel(const float* __restrict__ Q,
                                                     uint16_t* __restrict__ Qt,
                                                     float* __restrict__ out) {
    // T[c8 8][i 32][j 33] f32, c8-stride 1064 so bank = 8*c8 + i + j
    __shared__ float T[8 * 1064];
    const int ch = blockIdx.x, b = blockIdx.y;
    const int tid = threadIdx.x;

    // fold in out-zeroing: 512 blocks x 256 threads = 131072 >= 67600
    {
        int g = (b * 32 + ch) * 256 + tid;
        if (g < 67600) out[g] = 0.f;
    }

    const float* src = Q + ((size_t)(b * 256 + ch * 8)) * 1024;
    #pragma unroll
    for (int it = 0; it < 32; ++it) {                  // 8192 f32, coalesced
        int r = tid + it * 256;
        int c8 = r >> 10, rem = r & 1023;
        T[c8 * 1064 + (rem >> 5) * 33 + (rem & 31)] = src[(size_t)c8 * 1024 + rem];
    }
    __syncthreads();

    uint32_t* dst = (uint32_t*)Qt;                     // write bf16 pairs
    #pragma unroll
    for (int it = 0; it < 16; ++it) {                  // 4096 pairs
        int o2 = tid + it * 256;
        int t  = (o2 & 3) * 2;
        int il = (o2 >> 2) & 15;
        int j  = (o2 >> 6) & 31;
        int ih = (o2 >> 11) & 1;
        float v0 = T[t * 1064 + (ih * 16 + il) * 33 + j];
        float v1 = T[(t + 1) * 1064 + (ih * 16 + il) * 33 + j];
        uint32_t pk = (uint32_t)f2bf(v0) | ((uint32_t)f2bf(v1) << 16);
        size_t oi = ((((size_t)(b * 2 + ih) * 32 + j) * 32 + ch) * 16 + il) * 4 + (t >> 1);
        dst[oi] = pk;
    }
}

// ---------------------------------------------------------------------------
// Kernel 2: round-7 structure (grid 1024, b=bid&15 XCD swizzle, 40 KB LDS,
// 4 blocks/CU, B-fragment ping-pong + sched_barrier(0)) + TWO deltas
// (round-11 resubmission -- r11 was a broker timeout, kernel never ran):
//   * T5: s_setprio(1)/(0) around each 18-MFMA cluster.  Round-10 analysis:
//     per-wave duty ~66% but MfmaUtil ~= one wave's duty -> co-resident waves
//     convoy (stall on the same resources at the same time).  Waves here are
//     free-running (no intra-loop barriers) = the attn-like regime where T5
//     measured +4-7% (m191); null only in barrier-lockstep GEMM (m190).
//   * epilogue Pw XOR-swizzle (stored group = logical ^ (row&3)): the Pw
//     writes at row-stride 80 f32 are an 8-way bank conflict = the constant
//     1.455M conflict cycles.  2-bit XOR cuts it to <=4-way.
// REGISTER DISCIPLINE (r1/r8/r10 law): live state beyond acc(40 AGPR) +
// ONE ping-pong set(32) + A(20) + addressing spills at (256,4).  Do NOT add
// prefetch state; do NOT raise launch-bounds occupancy (r2).
// ---------------------------------------------------------------------------
__global__ __launch_bounds__(256, 4) void corr_kernel(const float* __restrict__ S,
                                                      const uint16_t* __restrict__ Qt,
                                                      float* __restrict__ out) {
    __shared__ __align__(16) char smem[40960];         // 40 KB -> 4 blocks/CU
    uint16_t* S_l = (uint16_t*)smem;                   // [ch][row]: idx = ch*640 + row*8
    float*    Pw  = (float*)smem;                      // overlay: [4][iv 32][x 80]

    const int bid = blockIdx.x;
    const int b = bid & 15, d = bid >> 4;
    const int tid = threadIdx.x, wave = tid >> 6, lane = tid & 63;
    const int l15 = lane & 15, l4 = lane >> 4;

    // ---- zero-fill pad rows 0..15 for all ch (8 KB)
    {
        const u32x4 z = {};
        for (int zi = tid; zi < 512; zi += 256) {
            int ch = zi >> 4, r = zi & 15;
            *(u32x4*)&S_l[ch * 640 + r * 8] = z;
        }
    }
    // ---- stage S[b,:,d,:] -> S_l[ch][sx+16] (bf16). Writes lane-contiguous.
    {
        const int sx = tid & 63, w = tid >> 6;
        const float* sp = S + ((size_t)b * 256) * 4096 + (size_t)d * 64;
        #pragma unroll
        for (int k = 0; k < 8; ++k) {
            int ch = w * 8 + k;
            float v[8];
            #pragma unroll
            for (int cc = 0; cc < 8; ++cc)
                v[cc] = sp[(size_t)(ch * 8 + cc) * 4096 + sx];   // 256B coalesced
            u32x4 pk;
            #pragma unroll
            for (int q = 0; q < 4; ++q)
                pk[q] = (uint32_t)f2bf(v[2 * q]) | ((uint32_t)f2bf(v[2 * q + 1]) << 16);
            *(u32x4*)&S_l[ch * 640 + (sx + 16) * 8] = pk;        // contiguous 1KB/wave
        }
    }

    // ---- B-fragment base.  Body (jj,s): off = (wave+jj*4)*4096 + s*512.
    //      Fragments: +0 (ih0,j0a), +131072 (ih1,j0a), +65536 (ih0,j0b),
    //      +196608 (ih1,j0b).
    const uint16_t* Bb = Qt + (size_t)b * 262144 + l4 * 128 + l15 * 8;

    // prefetch body 0's B-fragments BEFORE the barrier (no LDS dependency)
    bf16x8 C0, C1, C2, C3;
    {
        const int s0 = (2 * wave) & 7;
        const uint16_t* p0 = Bb + wave * 4096 + s0 * 512;
        C0 = *(const bf16x8*)(p0);
        C1 = *(const bf16x8*)(p0 + 131072);
        C2 = *(const bf16x8*)(p0 + 65536);
        C3 = *(const bf16x8*)(p0 + 196608);
    }

    __syncthreads();

    f32x4 acc[5][2] = {};

    #pragma unroll
    for (int n = 0; n < 32; ++n) {
        const int jj = n >> 3;
        const int s  = ((n & 7) + 2 * wave) & 7;       // per-wave s-rotation
        const int j0a = wave + jj * 4;                 // 0..15 ; j0b = j0a+16

        // ---- issue NEXT body's B-loads (ping-pong).  Branchless clamp:
        // n=31 re-loads body 31 (results dead afterwards).
        const int nn = (n < 31) ? (n + 1) : 31;
        const int jn = nn >> 3;
        const int sn = ((nn & 7) + 2 * wave) & 7;
        const uint16_t* pn = Bb + (wave + jn * 4) * 4096 + sn * 512;
        bf16x8 N0 = *(const bf16x8*)(pn);
        bf16x8 N1 = *(const bf16x8*)(pn + 131072);
        bf16x8 N2 = *(const bf16x8*)(pn + 65536);
        bf16x8 N3 = *(const bf16x8*)(pn + 196608);

        // ---- A fragments from LDS (conflict-free b128), current body
        const int chb = (s * 4 + l4) * 640;
        bf16x8 A[5];
        #pragma unroll
        for (int t = 0; t < 5; ++t) {
            int rr = j0a + t * 16 + l15;               // <= 94
            rr = (rr < 80) ? rr : 0;                   // OOB -> zero-row
            A[t] = *(const bf16x8*)&S_l[chb + rr * 8];
        }
        __builtin_amdgcn_sched_barrier(0);             // do NOT sink the loads

        // ---- 18 MFMAs on the CURRENT (previously prefetched) B-fragments,
        // wrapped in setprio so an MFMA-phase wave wins CU arbitration (T5)
        __builtin_amdgcn_s_setprio(1);
        #pragma unroll
        for (int t = 0; t < 5; ++t) {
            acc[t][0] = __builtin_amdgcn_mfma_f32_16x16x32_bf16(A[t], C0, acc[t][0], 0, 0, 0);
            acc[t][1] = __builtin_amdgcn_mfma_f32_16x16x32_bf16(A[t], C1, acc[t][1], 0, 0, 0);
        }
        #pragma unroll
        for (int t = 1; t < 5; ++t) {
            acc[t - 1][0] = __builtin_amdgcn_mfma_f32_16x16x32_bf16(A[t], C2, acc[t - 1][0], 0, 0, 0);
            acc[t - 1][1] = __builtin_amdgcn_mfma_f32_16x16x32_bf16(A[t], C3, acc[t - 1][1], 0, 0, 0);
        }
        __builtin_amdgcn_s_setprio(0);

        C0 = N0; C1 = N1; C2 = N2; C3 = N3;
    }

    // ---- merge 4 wave-partials in LDS (XOR-swizzled groups), then atomics
    __syncthreads();
    {
        float* pw = Pw + wave * 2560;                  // [iv 32][x 80], swizzled
        #pragma unroll
        for (int m = 0; m < 5; ++m)
            #pragma unroll
            for (int n = 0; n < 2; ++n) {
                const int row = n * 16 + l15;
                const int grp = m * 4 + (l4 ^ (l15 & 3));   // stored = logical^(row&3)
                *(f32x4*)&pw[row * 80 + grp * 4] = acc[m][n];
            }
    }
    __syncthreads();
    for (int e = tid; e < 65 * 32; e += 256) {
        int x = e % 65, i = e / 65;
        int y = d - i + 16;
        if ((unsigned)y < 65u) {
            const int gx = ((((x >> 2) ^ (i & 3)) << 2) | (x & 3));  // un-swizzle
            const int o  = i * 80 + gx;
            float v = Pw[0 * 2560 + o] + Pw[1 * 2560 + o]
                    + Pw[2 * 2560 + o] + Pw[3 * 2560 + o];
            atomicAdd(out + ((size_t)b * 4225 + (size_t)y * 65 + x), v);
        }
    }
}

// ---------------------------------------------------------------------------
// fp32 fallback (only if workspace is too small) — slow but exact
// ---------------------------------------------------------------------------
__global__ __launch_bounds__(256) void naive_kernel(const float* __restrict__ Q,
                                                    const float* __restrict__ S,
                                                    float* __restrict__ out) {
    int gid = blockIdx.x * 256 + threadIdx.x;
    if (gid >= 67600) return;
    int b = gid / 4225, r = gid % 4225, y = r / 65, x = r % 65;
    int jlo = 16 - x; if (jlo < 0) jlo = 0;
    int jhi = 80 - x; if (jhi > 32) jhi = 32;
    float acc = 0.f;
    for (int c = 0; c < 256; ++c) {
        const float* Sb = S + ((size_t)(b * 256 + c)) * 4096;
        const float* Qb = Q + ((size_t)(b * 256 + c)) * 1024;
        for (int i = 0; i < 32; ++i) {
            int dd = y + i - 16;
            if ((unsigned)dd >= 64u) continue;
            const float* Sr = Sb + dd * 64 + (x - 16);
            const float* Qr = Qb + i * 32;
            for (int j = jlo; j < jhi; ++j) acc += Sr[j] * Qr[j];
        }
    }
    out[gid] = acc;
}

extern "C" void kernel_launch(void* const* d_in, const int* in_sizes, int n_in,
                              void* d_out, int out_size, void* d_ws, size_t ws_size,
                              hipStream_t stream) {
    (void)in_sizes; (void)n_in; (void)out_size;
    const float* Q = (const float*)d_in[0];   // [16,256,32,32] f32
    const float* S = (const float*)d_in[1];   // [16,256,64,64] f32
    float* out = (float*)d_out;               // [16,1,65,65] f32

    const size_t QT_BYTES = (size_t)16 * 2 * 32 * 32 * 16 * 8 * 2;  // 8,388,608

    if (ws_size < QT_BYTES) {
        naive_kernel<<<(67600 + 255) / 256, 256, 0, stream>>>(Q, S, out);
        return;
    }
    uint16_t* Qt = (uint16_t*)d_ws;

    qtrans_kernel<<<dim3(32, 16), 256, 0, stream>>>(Q, Qt, out);
    corr_kernel<<<1024, 256, 0, stream>>>(S, Qt, out);
}